// Round 2
// baseline (266.915 us; speedup 1.0000x reference)
//
#include <hip/hip_runtime.h>

#define B_    8
#define S_    1024
#define H_    12
#define DH_   64
#define D_    768
#define NQKV_ 2304
#define BS_   8192

typedef unsigned short u16;
typedef __attribute__((ext_vector_type(2))) unsigned short u16x2;
typedef __attribute__((ext_vector_type(4))) unsigned short u16x4;
typedef __attribute__((ext_vector_type(8))) short short8;
typedef __attribute__((ext_vector_type(4))) float f32x4;

#define MFMA16(a, b, c) __builtin_amdgcn_mfma_f32_16x16x32_bf16((a), (b), (c), 0, 0, 0)

__device__ __forceinline__ u16 f2bf(float f) {
  unsigned u = __builtin_bit_cast(unsigned, f);
  u += 0x7fffu + ((u >> 16) & 1u);   // round-to-nearest-even
  return (u16)(u >> 16);
}

// ---------------------------------------------------------------- x -> bf16
__global__ __launch_bounds__(256) void cvt_x_kernel(const float* __restrict__ x,
                                                    u16* __restrict__ xb) {
  int i = (blockIdx.x * 256 + threadIdx.x) * 4;
  float4 v = *(const float4*)(x + i);
  u16x4 o = { f2bf(v.x), f2bf(v.y), f2bf(v.z), f2bf(v.w) };
  *(u16x4*)(xb + i) = o;
}

// ------------------------------------- W (3x [768,768]) -> bf16, transposed
// wbt[n][k] = W[k][n], n in [0,2304) over {WQ,WK,WV}
__global__ __launch_bounds__(256) void cvt_w_kernel(const float* __restrict__ WQ,
                                                    const float* __restrict__ WK,
                                                    const float* __restrict__ WV,
                                                    u16* __restrict__ wbt) {
  __shared__ float tile[32][33];
  const float* W = (blockIdx.z == 0) ? WQ : (blockIdx.z == 1 ? WK : WV);
  int k0 = blockIdx.x * 32, n0 = blockIdx.y * 32;
  int tx = threadIdx.x, ty = threadIdx.y;
#pragma unroll
  for (int i = 0; i < 4; i++) {
    int r = ty + 8 * i;
    tile[r][tx] = W[(k0 + r) * D_ + n0 + tx];
  }
  __syncthreads();
#pragma unroll
  for (int i = 0; i < 4; i++) {
    int rr = ty + 8 * i;
    wbt[(blockIdx.z * D_ + n0 + rr) * D_ + k0 + tx] = f2bf(tile[tx][rr]);
  }
}

// ----------------------------------------------- QKV = Xb @ Wbt^T  (bf16 out)
// C[8192][2304]; tile 128x128, BK=32, 4 waves each computing 64x64.
// Q region (col<768) scaled by 1/sqrt(dh)=0.125 at epilogue.
__global__ __launch_bounds__(256) void gemm_qkv_kernel(const u16* __restrict__ xb,
                                                       const u16* __restrict__ wbt,
                                                       u16* __restrict__ qkv) {
  __shared__ u16 At[128 * 40];   // [128 rows][32 k] padded to 40
  __shared__ u16 Bt[128 * 40];   // [128 cols][32 k] padded to 40
  const int m0 = blockIdx.y * 128, n0 = blockIdx.x * 128;
  const int t = threadIdx.x;
  const int lane = t & 63, w = t >> 6;
  const int g = lane >> 4, r15 = lane & 15;
  const int wr = w >> 1, wc = w & 1;

  f32x4 acc[4][4];
#pragma unroll
  for (int m = 0; m < 4; m++)
#pragma unroll
    for (int n = 0; n < 4; n++) acc[m][n] = f32x4{0.f, 0.f, 0.f, 0.f};

  for (int kt = 0; kt < D_ / 32; kt++) {
    __syncthreads();
#pragma unroll
    for (int i = 0; i < 2; i++) {
      int c = t + 256 * i;
      int row = c >> 2, cb = c & 3;
      *(short8*)(At + row * 40 + cb * 8) =
          *(const short8*)(xb + (m0 + row) * D_ + kt * 32 + cb * 8);
      *(short8*)(Bt + row * 40 + cb * 8) =
          *(const short8*)(wbt + (n0 + row) * D_ + kt * 32 + cb * 8);
    }
    __syncthreads();
    short8 a[4], b[4];
#pragma unroll
    for (int m = 0; m < 4; m++)
      a[m] = *(const short8*)(At + (wr * 64 + m * 16 + r15) * 40 + g * 8);
#pragma unroll
    for (int n = 0; n < 4; n++)
      b[n] = *(const short8*)(Bt + (wc * 64 + n * 16 + r15) * 40 + g * 8);
#pragma unroll
    for (int m = 0; m < 4; m++)
#pragma unroll
      for (int n = 0; n < 4; n++) acc[m][n] = MFMA16(a[m], b[n], acc[m][n]);
  }

#pragma unroll
  for (int m = 0; m < 4; m++) {
#pragma unroll
    for (int n = 0; n < 4; n++) {
      int col = n0 + wc * 64 + n * 16 + r15;
      float scale = (col < D_) ? 0.125f : 1.0f;  // fold 1/sqrt(64) into Q
#pragma unroll
      for (int r = 0; r < 4; r++) {
        int row = m0 + wr * 64 + m * 16 + g * 4 + r;
        qkv[row * NQKV_ + col] = f2bf(acc[m][n][r] * scale);
      }
    }
  }
}

// ------------------------------------------------------- flash attention
// block = (b, h, 64 q-rows); 4 waves x 16 q-rows; KV tiles of 64.
__global__ __launch_bounds__(256) void attn_kernel(const u16* __restrict__ qkv,
                                                   float* __restrict__ out) {
  __shared__ u16 Kt[64 * 72];        // [kv][dh] padded 72
  __shared__ u16 Vt[64 * 72];        // [dh][kv] padded 72 (transposed)
  __shared__ u16 Pl[4 * 16 * 72];    // per-wave P tile [16 q][64 kv] padded 72

  const int b = blockIdx.z, h = blockIdx.y, q0 = blockIdx.x * 64;
  const int t = threadIdx.x;
  const int lane = t & 63, w = t >> 6;
  const int g = lane >> 4, r15 = lane & 15;

  // Q fragments stay in registers (Q already scaled by 0.125)
  const int gq = b * S_ + q0 + w * 16 + r15;
  const short8 qf0 = *(const short8*)(qkv + gq * NQKV_ + h * 64 + g * 8);
  const short8 qf1 = *(const short8*)(qkv + gq * NQKV_ + h * 64 + 32 + g * 8);

  f32x4 o[4];
#pragma unroll
  for (int n = 0; n < 4; n++) o[n] = f32x4{0.f, 0.f, 0.f, 0.f};
  float mrun[4], lrun[4];
#pragma unroll
  for (int r = 0; r < 4; r++) { mrun[r] = -1e30f; lrun[r] = 0.f; }

  u16* Pw = Pl + w * 16 * 72;

  for (int kb = 0; kb < S_ / 64; kb++) {
    __syncthreads();
    // ---- stage K tile [64][64] row-major
    const u16* kbase = qkv + (b * S_ + kb * 64) * NQKV_ + D_ + h * 64;
#pragma unroll
    for (int i = 0; i < 2; i++) {
      int c = t + 256 * i;
      int row = c >> 3, cb = c & 7;
      *(short8*)(Kt + row * 72 + cb * 8) = *(const short8*)(kbase + row * NQKV_ + cb * 8);
    }
    // ---- stage V tile transposed: Vt[d][kv]
    const u16* vbase = qkv + (b * S_ + kb * 64) * NQKV_ + 2 * D_ + h * 64;
#pragma unroll
    for (int i = 0; i < 8; i++) {
      int idx2 = t + 256 * i;
      int kv = idx2 >> 5, d2 = (idx2 & 31) * 2;
      u16x2 v = *(const u16x2*)(vbase + kv * NQKV_ + d2);
      Vt[d2 * 72 + kv] = v.x;
      Vt[(d2 + 1) * 72 + kv] = v.y;
    }
    __syncthreads();

    // ---- S = Q K^T : 4 kv-groups of 16
    f32x4 s[4];
#pragma unroll
    for (int n = 0; n < 4; n++) {
      short8 k0f = *(const short8*)(Kt + (n * 16 + r15) * 72 + g * 8);
      short8 k1f = *(const short8*)(Kt + (n * 16 + r15) * 72 + 32 + g * 8);
      f32x4 z = f32x4{0.f, 0.f, 0.f, 0.f};
      z = MFMA16(qf0, k0f, z);
      z = MFMA16(qf1, k1f, z);
      s[n] = z;
    }

    // ---- online softmax (rows = g*4+r, reduce over 16 lanes of r15)
    float mx[4];
#pragma unroll
    for (int r = 0; r < 4; r++)
      mx[r] = fmaxf(fmaxf(s[0][r], s[1][r]), fmaxf(s[2][r], s[3][r]));
#pragma unroll
    for (int off = 1; off < 16; off <<= 1)
#pragma unroll
      for (int r = 0; r < 4; r++) mx[r] = fmaxf(mx[r], __shfl_xor(mx[r], off));

    float p[4][4], al[4], rs[4];
#pragma unroll
    for (int r = 0; r < 4; r++) {
      float mn = fmaxf(mrun[r], mx[r]);
      al[r] = __expf(mrun[r] - mn);
      mrun[r] = mn;
      float acc = 0.f;
#pragma unroll
      for (int n = 0; n < 4; n++) { p[n][r] = __expf(s[n][r] - mn); acc += p[n][r]; }
      rs[r] = acc;
    }
#pragma unroll
    for (int off = 1; off < 16; off <<= 1)
#pragma unroll
      for (int r = 0; r < 4; r++) rs[r] += __shfl_xor(rs[r], off);
#pragma unroll
    for (int r = 0; r < 4; r++) lrun[r] = lrun[r] * al[r] + rs[r];
#pragma unroll
    for (int n = 0; n < 4; n++)
#pragma unroll
      for (int r = 0; r < 4; r++) o[n][r] *= al[r];

    // ---- P -> LDS (bf16), re-fragment as PV A-operand
#pragma unroll
    for (int n = 0; n < 4; n++)
#pragma unroll
      for (int r = 0; r < 4; r++)
        Pw[(g * 4 + r) * 72 + n * 16 + r15] = f2bf(p[n][r]);
    __syncthreads();

    short8 pa0 = *(const short8*)(Pw + r15 * 72 + g * 8);
    short8 pa1 = *(const short8*)(Pw + r15 * 72 + 32 + g * 8);
#pragma unroll
    for (int n = 0; n < 4; n++) {
      short8 v0 = *(const short8*)(Vt + (n * 16 + r15) * 72 + g * 8);
      short8 v1 = *(const short8*)(Vt + (n * 16 + r15) * 72 + 32 + g * 8);
      o[n] = MFMA16(pa0, v0, o[n]);
      o[n] = MFMA16(pa1, v1, o[n]);
    }
  }

  // ---- epilogue: O / l, fp32 out [B,S,H*dh]
  const int orow = b * S_ + q0 + w * 16;
#pragma unroll
  for (int n = 0; n < 4; n++)
#pragma unroll
    for (int r = 0; r < 4; r++)
      out[(orow + g * 4 + r) * D_ + h * 64 + n * 16 + r15] = o[n][r] / lrun[r];
}

// ---------------------------------------------------------------- launcher
extern "C" void kernel_launch(void* const* d_in, const int* in_sizes, int n_in,
                              void* d_out, int out_size, void* d_ws, size_t ws_size,
                              hipStream_t stream) {
  const float* x  = (const float*)d_in[0];
  const float* WQ = (const float*)d_in[1];
  const float* WK = (const float*)d_in[2];
  const float* WV = (const float*)d_in[3];
  float* out = (float*)d_out;

  u16* xb  = (u16*)d_ws;                       // [8192][768] bf16
  u16* wbt = xb + (size_t)BS_ * D_;            // [2304][768] bf16 (W^T)
  u16* qkv = wbt + (size_t)NQKV_ * D_;         // [8192][2304] bf16

  cvt_x_kernel<<<BS_ * D_ / 4 / 256, 256, 0, stream>>>(x, xb);
  cvt_w_kernel<<<dim3(D_ / 32, D_ / 32, 3), dim3(32, 8), 0, stream>>>(WQ, WK, WV, wbt);
  gemm_qkv_kernel<<<dim3(NQKV_ / 128, BS_ / 128), 256, 0, stream>>>(xb, wbt, qkv);
  attn_kernel<<<dim3(S_ / 64, H_, B_), 256, 0, stream>>>(qkv, out);
}

// Round 4
// 227.712 us; speedup vs baseline: 1.1722x; 1.1722x over previous
//
#include <hip/hip_runtime.h>

#define B_    8
#define S_    1024
#define H_    12
#define DH_   64
#define D_    768
#define NQKV_ 2304
#define BS_   8192

typedef unsigned short u16;
typedef __attribute__((ext_vector_type(2))) unsigned short u16x2;
typedef __attribute__((ext_vector_type(4))) unsigned short u16x4;
typedef __attribute__((ext_vector_type(8))) short short8;
typedef __attribute__((ext_vector_type(4))) float f32x4;

#define MFMA16(a, b, c) __builtin_amdgcn_mfma_f32_16x16x32_bf16((a), (b), (c), 0, 0, 0)

__device__ __forceinline__ u16 f2bf(float f) {
  unsigned u = __builtin_bit_cast(unsigned, f);
  u += 0x7fffu + ((u >> 16) & 1u);   // round-to-nearest-even
  return (u16)(u >> 16);
}

// async global->LDS, 16B per lane; dest must be linear (base + lane*16)
__device__ __forceinline__ void gl_lds16(const u16* g, u16* l) {
  __builtin_amdgcn_global_load_lds(
      (const __attribute__((address_space(1))) unsigned int*)g,
      (__attribute__((address_space(3))) unsigned int*)l, 16, 0, 0);
}

// ---------------------------------------------------------------- x -> bf16
__global__ __launch_bounds__(256) void cvt_x_kernel(const float* __restrict__ x,
                                                    u16* __restrict__ xb) {
  int i = (blockIdx.x * 256 + threadIdx.x) * 4;
  float4 v = *(const float4*)(x + i);
  u16x4 o = { f2bf(v.x), f2bf(v.y), f2bf(v.z), f2bf(v.w) };
  *(u16x4*)(xb + i) = o;
}

// ------------------------------------- W (3x [768,768]) -> bf16, transposed
__global__ __launch_bounds__(256) void cvt_w_kernel(const float* __restrict__ WQ,
                                                    const float* __restrict__ WK,
                                                    const float* __restrict__ WV,
                                                    u16* __restrict__ wbt) {
  __shared__ float tile[32][33];
  const float* W = (blockIdx.z == 0) ? WQ : (blockIdx.z == 1 ? WK : WV);
  int k0 = blockIdx.x * 32, n0 = blockIdx.y * 32;
  int tx = threadIdx.x, ty = threadIdx.y;
#pragma unroll
  for (int i = 0; i < 4; i++) {
    int r = ty + 8 * i;
    tile[r][tx] = W[(k0 + r) * D_ + n0 + tx];
  }
  __syncthreads();
#pragma unroll
  for (int i = 0; i < 4; i++) {
    int rr = ty + 8 * i;
    wbt[(blockIdx.z * D_ + n0 + rr) * D_ + k0 + tx] = f2bf(tile[tx][rr]);
  }
}

// ----------------------------------------------- QKV = Xb @ Wbt^T  (bf16 out)
// 128x128 tile, BK=64, global_load_lds w16, XOR-chunk LDS swizzle (rule 21).
__global__ __launch_bounds__(256) void gemm_qkv_kernel(const u16* __restrict__ xb,
                                                       const u16* __restrict__ wbt,
                                                       u16* __restrict__ qkv) {
  __shared__ u16 At[128 * 64];   // linear; chunk c' = c ^ (row&7) holds global chunk c
  __shared__ u16 Bt[128 * 64];
  const int m0 = blockIdx.y * 128, n0 = blockIdx.x * 128;
  const int t = threadIdx.x;
  const int lane = t & 63, w = t >> 6;
  const int g = lane >> 4, r15 = lane & 15;
  const int wr = w >> 1, wc = w & 1;

  f32x4 acc[4][4];
#pragma unroll
  for (int m = 0; m < 4; m++)
#pragma unroll
    for (int n = 0; n < 4; n++) acc[m][n] = f32x4{0.f, 0.f, 0.f, 0.f};

  for (int kt = 0; kt < D_ / 64; kt++) {
    __syncthreads();
#pragma unroll
    for (int i = 0; i < 4; i++) {
      int c = t + 256 * i;            // chunk id, 16B each
      int row = c >> 3, cb = c & 7;
      int sc = cb ^ (row & 7);        // pre-swizzled global source
      gl_lds16(xb + (size_t)(m0 + row) * D_ + kt * 64 + sc * 8, At + c * 8);
      gl_lds16(wbt + (size_t)(n0 + row) * D_ + kt * 64 + sc * 8, Bt + c * 8);
    }
    __syncthreads();

    short8 a[2][4], b[2][4];
#pragma unroll
    for (int ks = 0; ks < 2; ks++) {
#pragma unroll
      for (int m = 0; m < 4; m++) {
        int ra = wr * 64 + m * 16 + r15;
        a[ks][m] = *(const short8*)(At + ra * 64 + (((ks * 4 + g) ^ (ra & 7)) * 8));
        int rb = wc * 64 + m * 16 + r15;
        b[ks][m] = *(const short8*)(Bt + rb * 64 + (((ks * 4 + g) ^ (rb & 7)) * 8));
      }
    }
#pragma unroll
    for (int ks = 0; ks < 2; ks++)
#pragma unroll
      for (int m = 0; m < 4; m++)
#pragma unroll
        for (int n = 0; n < 4; n++) acc[m][n] = MFMA16(a[ks][m], b[ks][n], acc[m][n]);
  }

#pragma unroll
  for (int m = 0; m < 4; m++) {
#pragma unroll
    for (int n = 0; n < 4; n++) {
      int col = n0 + wc * 64 + n * 16 + r15;
      float scale = (col < D_) ? 0.125f : 1.0f;  // fold 1/sqrt(64) into Q
#pragma unroll
      for (int r = 0; r < 4; r++) {
        int row = m0 + wr * 64 + m * 16 + g * 4 + r;
        qkv[(size_t)row * NQKV_ + col] = f2bf(acc[m][n][r] * scale);
      }
    }
  }
}

// ------------------------------------------------------- flash attention
// block = (b, h, 128 q-rows); 4 waves x 32 q-rows; KV tiles of 64.
__global__ __launch_bounds__(256) void attn_kernel(const u16* __restrict__ qkv,
                                                   float* __restrict__ out) {
  __shared__ u16 Kt[64 * 64];        // linear swizzled [kv][dh]
  __shared__ u16 Vt[64 * 66];        // transposed [dh][kv] pad 66 (odd dwords)
  __shared__ u16 Pl[4 * 32 * 72];    // per-wave P tile [32 q][64 kv] pad 72

  const int b = blockIdx.z, h = blockIdx.y, q0 = blockIdx.x * 128;
  const int t = threadIdx.x;
  const int lane = t & 63, w = t >> 6;
  const int g = lane >> 4, r15 = lane & 15;

  // Q fragments (2 m-tiles x 2 k-chunks), Q pre-scaled by 0.125
  short8 qf[2][2];
#pragma unroll
  for (int mi = 0; mi < 2; mi++) {
    int gq = b * S_ + q0 + w * 32 + mi * 16 + r15;
    qf[mi][0] = *(const short8*)(qkv + (size_t)gq * NQKV_ + h * 64 + g * 8);
    qf[mi][1] = *(const short8*)(qkv + (size_t)gq * NQKV_ + h * 64 + 32 + g * 8);
  }

  f32x4 o[2][4];
  float mrun[2][4], lrun[2][4];
#pragma unroll
  for (int mi = 0; mi < 2; mi++) {
#pragma unroll
    for (int n = 0; n < 4; n++) o[mi][n] = f32x4{0.f, 0.f, 0.f, 0.f};
#pragma unroll
    for (int r = 0; r < 4; r++) { mrun[mi][r] = -1e30f; lrun[mi][r] = 0.f; }
  }

  u16* Pw = Pl + w * 32 * 72;

  for (int kb = 0; kb < S_ / 64; kb++) {
    __syncthreads();
    // ---- K tile via global_load_lds, pre-swizzled source (rule 21)
    const u16* kbase = qkv + (size_t)(b * S_ + kb * 64) * NQKV_ + D_ + h * 64;
#pragma unroll
    for (int i = 0; i < 2; i++) {
      int c = t + 256 * i;
      int row = c >> 3, cb = c & 7;
      int sc = cb ^ (row & 7);
      gl_lds16(kbase + (size_t)row * NQKV_ + sc * 8, Kt + c * 8);
    }
    // ---- V tile transposed: Vt[d][kv], pad 66 (conflict-free)
    const u16* vbase = qkv + (size_t)(b * S_ + kb * 64) * NQKV_ + 2 * D_ + h * 64;
#pragma unroll
    for (int i = 0; i < 8; i++) {
      int idx2 = t + 256 * i;
      int kv = idx2 >> 5, d2 = (idx2 & 31) * 2;
      u16x2 v = *(const u16x2*)(vbase + (size_t)kv * NQKV_ + d2);
      Vt[d2 * 66 + kv] = v.x;
      Vt[(d2 + 1) * 66 + kv] = v.y;
    }
    __syncthreads();

    // ---- S = Q K^T (swizzled K reads)
    short8 kf[2][4];
#pragma unroll
    for (int n = 0; n < 4; n++) {
      int r = n * 16 + r15;
      kf[0][n] = *(const short8*)(Kt + r * 64 + ((g ^ (r & 7)) * 8));
      kf[1][n] = *(const short8*)(Kt + r * 64 + (((4 + g) ^ (r & 7)) * 8));
    }
    f32x4 s[2][4];
#pragma unroll
    for (int mi = 0; mi < 2; mi++)
#pragma unroll
      for (int n = 0; n < 4; n++) {
        f32x4 z = f32x4{0.f, 0.f, 0.f, 0.f};
        z = MFMA16(qf[mi][0], kf[0][n], z);
        z = MFMA16(qf[mi][1], kf[1][n], z);
        s[mi][n] = z;
      }

    // ---- online softmax (rows g*4+r per 16-lane group)
#pragma unroll
    for (int mi = 0; mi < 2; mi++) {
      float mx[4];
#pragma unroll
      for (int r = 0; r < 4; r++)
        mx[r] = fmaxf(fmaxf(s[mi][0][r], s[mi][1][r]), fmaxf(s[mi][2][r], s[mi][3][r]));
#pragma unroll
      for (int off = 1; off < 16; off <<= 1)
#pragma unroll
        for (int r = 0; r < 4; r++) mx[r] = fmaxf(mx[r], __shfl_xor(mx[r], off));

      float p[4][4], al[4], rs[4];
#pragma unroll
      for (int r = 0; r < 4; r++) {
        float mn = fmaxf(mrun[mi][r], mx[r]);
        al[r] = __expf(mrun[mi][r] - mn);
        mrun[mi][r] = mn;
        float acc = 0.f;
#pragma unroll
        for (int n = 0; n < 4; n++) { p[n][r] = __expf(s[mi][n][r] - mn); acc += p[n][r]; }
        rs[r] = acc;
      }
#pragma unroll
      for (int off = 1; off < 16; off <<= 1)
#pragma unroll
        for (int r = 0; r < 4; r++) rs[r] += __shfl_xor(rs[r], off);
#pragma unroll
      for (int r = 0; r < 4; r++) lrun[mi][r] = lrun[mi][r] * al[r] + rs[r];
#pragma unroll
      for (int n = 0; n < 4; n++)
#pragma unroll
        for (int r = 0; r < 4; r++) o[mi][n][r] *= al[r];

      // P -> per-wave LDS (no cross-wave sharing -> no barrier needed)
#pragma unroll
      for (int n = 0; n < 4; n++)
#pragma unroll
        for (int r = 0; r < 4; r++)
          Pw[(mi * 16 + g * 4 + r) * 72 + n * 16 + r15] = f2bf(p[n][r]);
    }

    // ---- O += P V
    short8 pa[2][2];
#pragma unroll
    for (int mi = 0; mi < 2; mi++) {
      pa[mi][0] = *(const short8*)(Pw + (mi * 16 + r15) * 72 + g * 8);
      pa[mi][1] = *(const short8*)(Pw + (mi * 16 + r15) * 72 + 32 + g * 8);
    }
#pragma unroll
    for (int n = 0; n < 4; n++) {
      short8 v0 = *(const short8*)(Vt + (n * 16 + r15) * 66 + g * 8);
      short8 v1 = *(const short8*)(Vt + (n * 16 + r15) * 66 + 32 + g * 8);
#pragma unroll
      for (int mi = 0; mi < 2; mi++) {
        o[mi][n] = MFMA16(pa[mi][0], v0, o[mi][n]);
        o[mi][n] = MFMA16(pa[mi][1], v1, o[mi][n]);
      }
    }
  }

  // ---- epilogue
  const int orow = b * S_ + q0 + w * 32;
#pragma unroll
  for (int mi = 0; mi < 2; mi++)
#pragma unroll
    for (int n = 0; n < 4; n++)
#pragma unroll
      for (int r = 0; r < 4; r++)
        out[(size_t)(orow + mi * 16 + g * 4 + r) * D_ + h * 64 + n * 16 + r15] =
            o[mi][n][r] / lrun[mi][r];
}

// ---------------------------------------------------------------- launcher
extern "C" void kernel_launch(void* const* d_in, const int* in_sizes, int n_in,
                              void* d_out, int out_size, void* d_ws, size_t ws_size,
                              hipStream_t stream) {
  const float* x  = (const float*)d_in[0];
  const float* WQ = (const float*)d_in[1];
  const float* WK = (const float*)d_in[2];
  const float* WV = (const float*)d_in[3];
  float* out = (float*)d_out;

  u16* xb  = (u16*)d_ws;                       // [8192][768] bf16
  u16* wbt = xb + (size_t)BS_ * D_;            // [2304][768] bf16 (W^T)
  u16* qkv = wbt + (size_t)NQKV_ * D_;         // [8192][2304] bf16

  cvt_x_kernel<<<BS_ * D_ / 4 / 256, 256, 0, stream>>>(x, xb);
  cvt_w_kernel<<<dim3(D_ / 32, D_ / 32, 3), dim3(32, 8), 0, stream>>>(WQ, WK, WV, wbt);
  gemm_qkv_kernel<<<dim3(NQKV_ / 128, BS_ / 128), 256, 0, stream>>>(xb, wbt, qkv);
  attn_kernel<<<dim3(S_ / 128, H_, B_), 256, 0, stream>>>(qkv, out);
}

// Round 5
// 209.366 us; speedup vs baseline: 1.2749x; 1.0876x over previous
//
#include <hip/hip_runtime.h>

#define B_    8
#define S_    1024
#define H_    12
#define DH_   64
#define D_    768
#define NQK_  1536
#define BS_   8192

typedef unsigned short u16;
typedef __attribute__((ext_vector_type(4))) unsigned short u16x4;
typedef __attribute__((ext_vector_type(8))) short short8;
typedef __attribute__((ext_vector_type(4))) float f32x4;

#define MFMA16(a, b, c) __builtin_amdgcn_mfma_f32_16x16x32_bf16((a), (b), (c), 0, 0, 0)

__device__ __forceinline__ u16 f2bf(float f) {
  unsigned u = __builtin_bit_cast(unsigned, f);
  u += 0x7fffu + ((u >> 16) & 1u);   // round-to-nearest-even
  return (u16)(u >> 16);
}

// async global->LDS, 16B per lane; dest must be linear (base + lane*16)
__device__ __forceinline__ void gl_lds16(const u16* g, u16* l) {
  __builtin_amdgcn_global_load_lds(
      (const __attribute__((address_space(1))) unsigned int*)g,
      (__attribute__((address_space(3))) unsigned int*)l, 16, 0, 0);
}

// ---------------------------------------------------------------- x -> bf16
__global__ __launch_bounds__(256) void cvt_x_kernel(const float* __restrict__ x,
                                                    u16* __restrict__ xb) {
  int i = (blockIdx.x * 256 + threadIdx.x) * 4;
  float4 v = *(const float4*)(x + i);
  u16x4 o = { f2bf(v.x), f2bf(v.y), f2bf(v.z), f2bf(v.w) };
  *(u16x4*)(xb + i) = o;
}

// ------------------------------------- W (3x [768,768]) -> bf16, transposed
__global__ __launch_bounds__(256) void cvt_w_kernel(const float* __restrict__ WQ,
                                                    const float* __restrict__ WK,
                                                    const float* __restrict__ WV,
                                                    u16* __restrict__ wbt) {
  __shared__ float tile[32][33];
  const float* W = (blockIdx.z == 0) ? WQ : (blockIdx.z == 1 ? WK : WV);
  int k0 = blockIdx.x * 32, n0 = blockIdx.y * 32;
  int tx = threadIdx.x, ty = threadIdx.y;
#pragma unroll
  for (int i = 0; i < 4; i++) {
    int r = ty + 8 * i;
    tile[r][tx] = W[(k0 + r) * D_ + n0 + tx];
  }
  __syncthreads();
#pragma unroll
  for (int i = 0; i < 4; i++) {
    int rr = ty + 8 * i;
    wbt[(blockIdx.z * D_ + n0 + rr) * D_ + k0 + tx] = f2bf(tile[tx][rr]);
  }
}

// ----------------------------------------------- QKV projection GEMM
// 128x128 tile, BK=64, global_load_lds w16, rule-21 XOR swizzle.
// Output: col-tiles 0..11 -> qk [8192][1536] (Q scaled 0.125);
//         col-tiles 12..17 -> vT [768][8192] (transposed via LDS).
// Epilogue re-stages C through LDS for coalesced short8 stores.
__global__ __launch_bounds__(256) void gemm_qkv_kernel(const u16* __restrict__ xb,
                                                       const u16* __restrict__ wbt,
                                                       u16* __restrict__ qk,
                                                       u16* __restrict__ vT) {
  __shared__ u16 sh[128 * 136];          // main: At|Bt (32KB); epilogue: C-tile
  u16* At = sh;
  u16* Bt = sh + 128 * 64;
  const int m0 = blockIdx.y * 128, n0 = blockIdx.x * 128;
  const int t = threadIdx.x;
  const int lane = t & 63, w = t >> 6;
  const int g = lane >> 4, r15 = lane & 15;
  const int wr = w >> 1, wc = w & 1;

  f32x4 acc[4][4];
#pragma unroll
  for (int m = 0; m < 4; m++)
#pragma unroll
    for (int n = 0; n < 4; n++) acc[m][n] = f32x4{0.f, 0.f, 0.f, 0.f};

  for (int kt = 0; kt < D_ / 64; kt++) {
    __syncthreads();
#pragma unroll
    for (int i = 0; i < 4; i++) {
      int c = t + 256 * i;            // 16B chunk id
      int row = c >> 3, cb = c & 7;
      int sc = cb ^ (row & 7);        // pre-swizzled global source (rule 21)
      gl_lds16(xb + (size_t)(m0 + row) * D_ + kt * 64 + sc * 8, At + c * 8);
      gl_lds16(wbt + (size_t)(n0 + row) * D_ + kt * 64 + sc * 8, Bt + c * 8);
    }
    __syncthreads();

    short8 a[2][4], b[2][4];
#pragma unroll
    for (int ks = 0; ks < 2; ks++) {
#pragma unroll
      for (int m = 0; m < 4; m++) {
        int ra = wr * 64 + m * 16 + r15;
        a[ks][m] = *(const short8*)(At + ra * 64 + (((ks * 4 + g) ^ (ra & 7)) * 8));
        int rb = wc * 64 + m * 16 + r15;
        b[ks][m] = *(const short8*)(Bt + rb * 64 + (((ks * 4 + g) ^ (rb & 7)) * 8));
      }
    }
#pragma unroll
    for (int ks = 0; ks < 2; ks++)
#pragma unroll
      for (int m = 0; m < 4; m++)
#pragma unroll
        for (int n = 0; n < 4; n++) acc[m][n] = MFMA16(a[ks][m], b[ks][n], acc[m][n]);
  }

  __syncthreads();                         // LDS reuse: staging done
  if (n0 < 2 * D_) {
    // ---- Q/K tile: C -> LDS [row][136] -> coalesced stores
    const float scale = (n0 < D_) ? 0.125f : 1.0f;   // whole tile uniform
#pragma unroll
    for (int m = 0; m < 4; m++)
#pragma unroll
      for (int n = 0; n < 4; n++)
#pragma unroll
        for (int r = 0; r < 4; r++)
          sh[(wr * 64 + m * 16 + g * 4 + r) * 136 + wc * 64 + n * 16 + r15] =
              f2bf(acc[m][n][r] * scale);
    __syncthreads();
#pragma unroll
    for (int i = 0; i < 8; i++) {
      int c2 = t + 256 * i;
      int row = c2 >> 4, cb = c2 & 15;
      *(short8*)(qk + (size_t)(m0 + row) * NQK_ + n0 + cb * 8) =
          *(const short8*)(sh + row * 136 + cb * 8);
    }
  } else {
    // ---- V tile: C^T -> LDS [col][136] -> coalesced stores to vT[768][8192]
#pragma unroll
    for (int m = 0; m < 4; m++)
#pragma unroll
      for (int n = 0; n < 4; n++)
#pragma unroll
        for (int r = 0; r < 4; r++)
          sh[(wc * 64 + n * 16 + r15) * 136 + wr * 64 + m * 16 + g * 4 + r] =
              f2bf(acc[m][n][r]);
    __syncthreads();
#pragma unroll
    for (int i = 0; i < 8; i++) {
      int c2 = t + 256 * i;
      int cc = c2 >> 4, rb = c2 & 15;
      *(short8*)(vT + (size_t)(n0 - 2 * D_ + cc) * BS_ + m0 + rb * 8) =
          *(const short8*)(sh + cc * 136 + rb * 8);
    }
  }
}

// ------------------------------------------------------- flash attention
// block = (b, h, 128 q-rows); 8 waves x 16 q-rows; KV tiles of 64.
// K from qk (cols 768..1535), V^T from vT — both via global_load_lds w16.
__global__ __launch_bounds__(512) void attn_kernel(const u16* __restrict__ qk,
                                                   const u16* __restrict__ vT,
                                                   float* __restrict__ out) {
  __shared__ u16 Kt[64 * 64];        // linear swizzled [kv][dh]
  __shared__ u16 Vt[64 * 64];        // linear swizzled [dh][kv]
  __shared__ u16 Pl[8 * 16 * 72];    // per-wave P tile [16 q][64 kv] pad 72

  const int b = blockIdx.z, h = blockIdx.y, q0 = blockIdx.x * 128;
  const int t = threadIdx.x;
  const int lane = t & 63, w = t >> 6;
  const int g = lane >> 4, r15 = lane & 15;

  // per-thread staging coords (one gl_lds16 each for K and V: 512 chunks)
  const int srow = t >> 3, scb = t & 7;
  const int ssc = scb ^ (srow & 7);

  // Q fragments in registers (Q pre-scaled by 0.125)
  const int gq = b * S_ + q0 + w * 16 + r15;
  const short8 qf0 = *(const short8*)(qk + (size_t)gq * NQK_ + h * 64 + g * 8);
  const short8 qf1 = *(const short8*)(qk + (size_t)gq * NQK_ + h * 64 + 32 + g * 8);

  f32x4 o[4];
#pragma unroll
  for (int n = 0; n < 4; n++) o[n] = f32x4{0.f, 0.f, 0.f, 0.f};
  float mrun[4], lrun[4];
#pragma unroll
  for (int r = 0; r < 4; r++) { mrun[r] = -1e30f; lrun[r] = 0.f; }

  u16* Pw = Pl + w * 16 * 72;

  for (int kb = 0; kb < S_ / 64; kb++) {
    __syncthreads();
    // K tile [kv][dh], pre-swizzled source
    gl_lds16(qk + (size_t)(b * S_ + kb * 64 + srow) * NQK_ + D_ + h * 64 + ssc * 8,
             Kt + t * 8);
    // V^T tile [dh][kv], pre-swizzled source
    gl_lds16(vT + (size_t)(h * 64 + srow) * BS_ + b * S_ + kb * 64 + ssc * 8,
             Vt + t * 8);
    __syncthreads();

    // ---- S = Q K^T (swizzled K reads)
    f32x4 s[4];
#pragma unroll
    for (int n = 0; n < 4; n++) {
      int r = n * 16 + r15;
      short8 k0f = *(const short8*)(Kt + r * 64 + ((g ^ (r & 7)) * 8));
      short8 k1f = *(const short8*)(Kt + r * 64 + (((4 + g) ^ (r & 7)) * 8));
      f32x4 z = f32x4{0.f, 0.f, 0.f, 0.f};
      z = MFMA16(qf0, k0f, z);
      z = MFMA16(qf1, k1f, z);
      s[n] = z;
    }

    // ---- online softmax (rows g*4+r, reduce across 16 lanes of r15)
    float mx[4];
#pragma unroll
    for (int r = 0; r < 4; r++)
      mx[r] = fmaxf(fmaxf(s[0][r], s[1][r]), fmaxf(s[2][r], s[3][r]));
#pragma unroll
    for (int off = 1; off < 16; off <<= 1)
#pragma unroll
      for (int r = 0; r < 4; r++) mx[r] = fmaxf(mx[r], __shfl_xor(mx[r], off));

    float p[4][4], al[4], rs[4];
#pragma unroll
    for (int r = 0; r < 4; r++) {
      float mn = fmaxf(mrun[r], mx[r]);
      al[r] = __expf(mrun[r] - mn);
      mrun[r] = mn;
      float acc = 0.f;
#pragma unroll
      for (int n = 0; n < 4; n++) { p[n][r] = __expf(s[n][r] - mn); acc += p[n][r]; }
      rs[r] = acc;
    }
#pragma unroll
    for (int off = 1; off < 16; off <<= 1)
#pragma unroll
      for (int r = 0; r < 4; r++) rs[r] += __shfl_xor(rs[r], off);
#pragma unroll
    for (int r = 0; r < 4; r++) lrun[r] = lrun[r] * al[r] + rs[r];
#pragma unroll
    for (int n = 0; n < 4; n++)
#pragma unroll
      for (int r = 0; r < 4; r++) o[n][r] *= al[r];

    // ---- P -> per-wave LDS (same-wave write/read: no barrier)
#pragma unroll
    for (int n = 0; n < 4; n++)
#pragma unroll
      for (int r = 0; r < 4; r++)
        Pw[(g * 4 + r) * 72 + n * 16 + r15] = f2bf(p[n][r]);

    short8 pa0 = *(const short8*)(Pw + r15 * 72 + g * 8);
    short8 pa1 = *(const short8*)(Pw + r15 * 72 + 32 + g * 8);
#pragma unroll
    for (int n = 0; n < 4; n++) {
      int r = n * 16 + r15;
      short8 v0 = *(const short8*)(Vt + r * 64 + ((g ^ (r & 7)) * 8));
      short8 v1 = *(const short8*)(Vt + r * 64 + (((4 + g) ^ (r & 7)) * 8));
      o[n] = MFMA16(pa0, v0, o[n]);
      o[n] = MFMA16(pa1, v1, o[n]);
    }
  }

  // ---- epilogue: O / l, fp32 out [B,S,H*dh]
  const int orow = b * S_ + q0 + w * 16;
#pragma unroll
  for (int n = 0; n < 4; n++)
#pragma unroll
    for (int r = 0; r < 4; r++)
      out[(size_t)(orow + g * 4 + r) * D_ + h * 64 + n * 16 + r15] = o[n][r] / lrun[r];
}

// ---------------------------------------------------------------- launcher
extern "C" void kernel_launch(void* const* d_in, const int* in_sizes, int n_in,
                              void* d_out, int out_size, void* d_ws, size_t ws_size,
                              hipStream_t stream) {
  const float* x  = (const float*)d_in[0];
  const float* WQ = (const float*)d_in[1];
  const float* WK = (const float*)d_in[2];
  const float* WV = (const float*)d_in[3];
  float* out = (float*)d_out;

  u16* xb  = (u16*)d_ws;                       // [8192][768]  bf16  (12.6 MB)
  u16* wbt = xb + (size_t)BS_ * D_;            // [2304][768]  bf16  ( 3.5 MB)
  u16* qk  = wbt + (size_t)3 * D_ * D_;        // [8192][1536] bf16  (25.2 MB)
  u16* vT  = qk + (size_t)BS_ * NQK_;          // [768][8192]  bf16  (12.6 MB)

  cvt_x_kernel<<<BS_ * D_ / 4 / 256, 256, 0, stream>>>(x, xb);
  cvt_w_kernel<<<dim3(D_ / 32, D_ / 32, 3), dim3(32, 8), 0, stream>>>(WQ, WK, WV, wbt);
  gemm_qkv_kernel<<<dim3(2304 / 128, BS_ / 128), 256, 0, stream>>>(xb, wbt, qk, vT);
  attn_kernel<<<dim3(S_ / 128, H_, B_), 512, 0, stream>>>(qk, vT, out);
}

// Round 6
// 205.002 us; speedup vs baseline: 1.3020x; 1.0213x over previous
//
#include <hip/hip_runtime.h>

#define B_    8
#define S_    1024
#define H_    12
#define DH_   64
#define D_    768
#define NQK_  1536
#define BS_   8192

typedef unsigned short u16;
typedef __attribute__((ext_vector_type(4))) unsigned short u16x4;
typedef __attribute__((ext_vector_type(8))) short short8;
typedef __attribute__((ext_vector_type(4))) float f32x4;

#define MFMA16(a, b, c) __builtin_amdgcn_mfma_f32_16x16x32_bf16((a), (b), (c), 0, 0, 0)

__device__ __forceinline__ u16 f2bf(float f) {
  unsigned u = __builtin_bit_cast(unsigned, f);
  u += 0x7fffu + ((u >> 16) & 1u);   // round-to-nearest-even
  return (u16)(u >> 16);
}

// async global->LDS, 16B per lane; dest must be linear (base + lane*16)
__device__ __forceinline__ void gl_lds16(const u16* g, u16* l) {
  __builtin_amdgcn_global_load_lds(
      (const __attribute__((address_space(1))) unsigned int*)g,
      (__attribute__((address_space(3))) unsigned int*)l, 16, 0, 0);
}

// ---------------------------------------------------------------- x -> bf16
__global__ __launch_bounds__(256) void cvt_x_kernel(const float* __restrict__ x,
                                                    u16* __restrict__ xb) {
  int i = (blockIdx.x * 256 + threadIdx.x) * 4;
  float4 v = *(const float4*)(x + i);
  u16x4 o = { f2bf(v.x), f2bf(v.y), f2bf(v.z), f2bf(v.w) };
  *(u16x4*)(xb + i) = o;
}

// ------------------------------------- W (3x [768,768]) -> bf16, transposed
__global__ __launch_bounds__(256) void cvt_w_kernel(const float* __restrict__ WQ,
                                                    const float* __restrict__ WK,
                                                    const float* __restrict__ WV,
                                                    u16* __restrict__ wbt) {
  __shared__ float tile[32][33];
  const float* W = (blockIdx.z == 0) ? WQ : (blockIdx.z == 1 ? WK : WV);
  int k0 = blockIdx.x * 32, n0 = blockIdx.y * 32;
  int tx = threadIdx.x, ty = threadIdx.y;
#pragma unroll
  for (int i = 0; i < 4; i++) {
    int r = ty + 8 * i;
    tile[r][tx] = W[(k0 + r) * D_ + n0 + tx];
  }
  __syncthreads();
#pragma unroll
  for (int i = 0; i < 4; i++) {
    int rr = ty + 8 * i;
    wbt[(blockIdx.z * D_ + n0 + rr) * D_ + k0 + tx] = f2bf(tile[tx][rr]);
  }
}

// ----------------------------------------------- QKV projection GEMM
// 128x128 tile, BK=64, global_load_lds w16, rule-21 XOR swizzle, T1 XCD swizzle.
// Q cols scaled by 0.125*log2(e) (softmax runs in exp2 domain).
__global__ __launch_bounds__(256) void gemm_qkv_kernel(const u16* __restrict__ xb,
                                                       const u16* __restrict__ wbt,
                                                       u16* __restrict__ qk,
                                                       u16* __restrict__ vT) {
  __shared__ u16 sh[128 * 136];          // main: At|Bt (32KB); epilogue: C-tile
  u16* At = sh;
  u16* Bt = sh + 128 * 64;
  // T1: 1152 blocks -> each XCD owns an 8(m) x 18(n) region
  const int f = blockIdx.x;
  const int wkid = (f & 7) * 144 + (f >> 3);
  const int m0 = (wkid / 18) * 128, n0 = (wkid % 18) * 128;
  const int t = threadIdx.x;
  const int lane = t & 63, w = t >> 6;
  const int g = lane >> 4, r15 = lane & 15;
  const int wr = w >> 1, wc = w & 1;

  f32x4 acc[4][4];
#pragma unroll
  for (int m = 0; m < 4; m++)
#pragma unroll
    for (int n = 0; n < 4; n++) acc[m][n] = f32x4{0.f, 0.f, 0.f, 0.f};

  for (int kt = 0; kt < D_ / 64; kt++) {
    __syncthreads();
#pragma unroll
    for (int i = 0; i < 4; i++) {
      int c = t + 256 * i;            // 16B chunk id
      int row = c >> 3, cb = c & 7;
      int sc = cb ^ (row & 7);        // pre-swizzled global source (rule 21)
      gl_lds16(xb + (size_t)(m0 + row) * D_ + kt * 64 + sc * 8, At + c * 8);
      gl_lds16(wbt + (size_t)(n0 + row) * D_ + kt * 64 + sc * 8, Bt + c * 8);
    }
    __syncthreads();

    short8 a[2][4], b[2][4];
#pragma unroll
    for (int ks = 0; ks < 2; ks++) {
#pragma unroll
      for (int m = 0; m < 4; m++) {
        int ra = wr * 64 + m * 16 + r15;
        a[ks][m] = *(const short8*)(At + ra * 64 + (((ks * 4 + g) ^ (ra & 7)) * 8));
        int rb = wc * 64 + m * 16 + r15;
        b[ks][m] = *(const short8*)(Bt + rb * 64 + (((ks * 4 + g) ^ (rb & 7)) * 8));
      }
    }
#pragma unroll
    for (int ks = 0; ks < 2; ks++)
#pragma unroll
      for (int m = 0; m < 4; m++)
#pragma unroll
        for (int n = 0; n < 4; n++) acc[m][n] = MFMA16(a[ks][m], b[ks][n], acc[m][n]);
  }

  __syncthreads();                         // LDS reuse: staging done
  if (n0 < 2 * D_) {
    // ---- Q/K tile: C -> LDS [row][136] -> coalesced stores
    // Q gets 1/sqrt(dh) * log2(e) so softmax uses exp2 directly
    const float scale = (n0 < D_) ? 0.125f * 1.4426950408889634f : 1.0f;
#pragma unroll
    for (int m = 0; m < 4; m++)
#pragma unroll
      for (int n = 0; n < 4; n++)
#pragma unroll
        for (int r = 0; r < 4; r++)
          sh[(wr * 64 + m * 16 + g * 4 + r) * 136 + wc * 64 + n * 16 + r15] =
              f2bf(acc[m][n][r] * scale);
    __syncthreads();
#pragma unroll
    for (int i = 0; i < 8; i++) {
      int c2 = t + 256 * i;
      int row = c2 >> 4, cb = c2 & 15;
      *(short8*)(qk + (size_t)(m0 + row) * NQK_ + n0 + cb * 8) =
          *(const short8*)(sh + row * 136 + cb * 8);
    }
  } else {
    // ---- V tile: C^T -> LDS [col][136] -> coalesced stores to vT[768][8192]
#pragma unroll
    for (int m = 0; m < 4; m++)
#pragma unroll
      for (int n = 0; n < 4; n++)
#pragma unroll
        for (int r = 0; r < 4; r++)
          sh[(wc * 64 + n * 16 + r15) * 136 + wr * 64 + m * 16 + g * 4 + r] =
              f2bf(acc[m][n][r]);
    __syncthreads();
#pragma unroll
    for (int i = 0; i < 8; i++) {
      int c2 = t + 256 * i;
      int cc = c2 >> 4, rb = c2 & 15;
      *(short8*)(vT + (size_t)(n0 - 2 * D_ + cc) * BS_ + m0 + rb * 8) =
          *(const short8*)(sh + cc * 136 + rb * 8);
    }
  }
}

// ------------------------------------------------------- flash attention
// block = (b, h, 128 q-rows); 8 waves x 16 q-rows; KV tiles of 64.
// Double-buffered K/V, one barrier/tile (stage overlaps compute).
// Softmax in exp2 domain, defer-max (THR=8), per-lane partial l.
__global__ __launch_bounds__(512) void attn_kernel(const u16* __restrict__ qk,
                                                   const u16* __restrict__ vT,
                                                   float* __restrict__ out) {
  __shared__ u16 Kt[2][64 * 64];     // linear swizzled [kv][dh]
  __shared__ u16 Vt[2][64 * 64];     // linear swizzled [dh][kv]
  __shared__ u16 Pl[8 * 16 * 72];    // per-wave P tile [16 q][64 kv] pad 72

  // T1: 768 blocks -> each XCD owns 12 whole (b,h) groups (K/V L2-resident)
  const int f = blockIdx.x;
  const int wkid = (f & 7) * 96 + (f >> 3);
  const int q0 = (wkid & 7) * 128;
  const int h  = (wkid >> 3) % H_;
  const int b  = wkid / (8 * H_);

  const int t = threadIdx.x;
  const int lane = t & 63, w = t >> 6;
  const int g = lane >> 4, r15 = lane & 15;

  // staging coords: 512 chunks each for K and V, 1 per thread
  const int srow = t >> 3, scb = t & 7;
  const int ssc = scb ^ (srow & 7);
  const u16* kbase = qk + (size_t)b * S_ * NQK_ + D_ + h * 64;
  const u16* vbase = vT + (size_t)(h * 64 + srow) * BS_ + b * S_;

#define STAGE(kb_, bu_)                                                        \
  do {                                                                         \
    gl_lds16(kbase + (size_t)((kb_) * 64 + srow) * NQK_ + ssc * 8,             \
             Kt[bu_] + t * 8);                                                 \
    gl_lds16(vbase + (kb_) * 64 + ssc * 8, Vt[bu_] + t * 8);                   \
  } while (0)

  STAGE(0, 0);

  // Q fragments in registers (Q pre-scaled by 0.125*log2e)
  const int gq = b * S_ + q0 + w * 16 + r15;
  const short8 qf0 = *(const short8*)(qk + (size_t)gq * NQK_ + h * 64 + g * 8);
  const short8 qf1 = *(const short8*)(qk + (size_t)gq * NQK_ + h * 64 + 32 + g * 8);

  f32x4 o[4];
#pragma unroll
  for (int n = 0; n < 4; n++) o[n] = f32x4{0.f, 0.f, 0.f, 0.f};
  float mrun[4], lrun[4];
#pragma unroll
  for (int r = 0; r < 4; r++) { mrun[r] = -1e30f; lrun[r] = 0.f; }

  u16* Pw = Pl + w * 16 * 72;

  for (int kb = 0; kb < S_ / 64; kb++) {
    __syncthreads();                 // drains vmcnt: buf[kb&1] ready, prev reads done
    if (kb < S_ / 64 - 1) STAGE(kb + 1, (kb + 1) & 1);
    const u16* Kc = Kt[kb & 1];
    const u16* Vc = Vt[kb & 1];

    // ---- S = Q K^T (swizzled K reads); scores in log2 domain
    f32x4 s[4];
#pragma unroll
    for (int n = 0; n < 4; n++) {
      int r = n * 16 + r15;
      short8 k0f = *(const short8*)(Kc + r * 64 + ((g ^ (r & 7)) * 8));
      short8 k1f = *(const short8*)(Kc + r * 64 + (((4 + g) ^ (r & 7)) * 8));
      f32x4 z = f32x4{0.f, 0.f, 0.f, 0.f};
      z = MFMA16(qf0, k0f, z);
      z = MFMA16(qf1, k1f, z);
      s[n] = z;
    }

    // ---- online softmax: rows g*4+r, reduce max across 16 lanes
    float mx[4];
#pragma unroll
    for (int r = 0; r < 4; r++)
      mx[r] = fmaxf(fmaxf(s[0][r], s[1][r]), fmaxf(s[2][r], s[3][r]));
#pragma unroll
    for (int off = 1; off < 16; off <<= 1)
#pragma unroll
      for (int r = 0; r < 4; r++) mx[r] = fmaxf(mx[r], __shfl_xor(mx[r], off));

    // defer-max: only rescale when max grew by >8 (P bounded by 2^8)
    float dmax = fmaxf(fmaxf(mx[0] - mrun[0], mx[1] - mrun[1]),
                       fmaxf(mx[2] - mrun[2], mx[3] - mrun[3]));
    const bool resc = __any(dmax > 8.0f);
    float al[4];
    if (resc) {
#pragma unroll
      for (int r = 0; r < 4; r++) {
        float mn = fmaxf(mrun[r], mx[r]);
        al[r] = exp2f(mrun[r] - mn);
        mrun[r] = mn;
      }
    }

    float p[4][4], rs[4];
#pragma unroll
    for (int r = 0; r < 4; r++) {
      float acc = 0.f;
#pragma unroll
      for (int n = 0; n < 4; n++) { p[n][r] = exp2f(s[n][r] - mrun[r]); acc += p[n][r]; }
      rs[r] = acc;                   // per-lane partial row-sum (reduced at epilogue)
    }
    if (resc) {
#pragma unroll
      for (int r = 0; r < 4; r++) lrun[r] = lrun[r] * al[r] + rs[r];
#pragma unroll
      for (int n = 0; n < 4; n++)
#pragma unroll
        for (int r = 0; r < 4; r++) o[n][r] *= al[r];
    } else {
#pragma unroll
      for (int r = 0; r < 4; r++) lrun[r] += rs[r];
    }

    // ---- P -> per-wave LDS (same-wave write/read: no barrier)
#pragma unroll
    for (int n = 0; n < 4; n++)
#pragma unroll
      for (int r = 0; r < 4; r++)
        Pw[(g * 4 + r) * 72 + n * 16 + r15] = f2bf(p[n][r]);

    short8 pa0 = *(const short8*)(Pw + r15 * 72 + g * 8);
    short8 pa1 = *(const short8*)(Pw + r15 * 72 + 32 + g * 8);
#pragma unroll
    for (int n = 0; n < 4; n++) {
      int r = n * 16 + r15;
      short8 v0 = *(const short8*)(Vc + r * 64 + ((g ^ (r & 7)) * 8));
      short8 v1 = *(const short8*)(Vc + r * 64 + (((4 + g) ^ (r & 7)) * 8));
      o[n] = MFMA16(pa0, v0, o[n]);
      o[n] = MFMA16(pa1, v1, o[n]);
    }
  }
#undef STAGE

  // ---- epilogue: reduce per-lane partial l across the 16-lane row group
#pragma unroll
  for (int off = 1; off < 16; off <<= 1)
#pragma unroll
    for (int r = 0; r < 4; r++) lrun[r] += __shfl_xor(lrun[r], off);

  const int orow = b * S_ + q0 + w * 16;
#pragma unroll
  for (int n = 0; n < 4; n++)
#pragma unroll
    for (int r = 0; r < 4; r++)
      out[(size_t)(orow + g * 4 + r) * D_ + h * 64 + n * 16 + r15] = o[n][r] / lrun[r];
}

// ---------------------------------------------------------------- launcher
extern "C" void kernel_launch(void* const* d_in, const int* in_sizes, int n_in,
                              void* d_out, int out_size, void* d_ws, size_t ws_size,
                              hipStream_t stream) {
  const float* x  = (const float*)d_in[0];
  const float* WQ = (const float*)d_in[1];
  const float* WK = (const float*)d_in[2];
  const float* WV = (const float*)d_in[3];
  float* out = (float*)d_out;

  u16* xb  = (u16*)d_ws;                       // [8192][768]  bf16  (12.6 MB)
  u16* wbt = xb + (size_t)BS_ * D_;            // [2304][768]  bf16  ( 3.5 MB)
  u16* qk  = wbt + (size_t)3 * D_ * D_;        // [8192][1536] bf16  (25.2 MB)
  u16* vT  = qk + (size_t)BS_ * NQK_;          // [768][8192]  bf16  (12.6 MB)

  cvt_x_kernel<<<BS_ * D_ / 4 / 256, 256, 0, stream>>>(x, xb);
  cvt_w_kernel<<<dim3(D_ / 32, D_ / 32, 3), dim3(32, 8), 0, stream>>>(WQ, WK, WV, wbt);
  gemm_qkv_kernel<<<1152, 256, 0, stream>>>(xb, wbt, qk, vT);
  attn_kernel<<<768, 512, 0, stream>>>(qk, vT, out);
}